// Round 11
// baseline (77.716 us; speedup 1.0000x reference)
//
#include <hip/hip_runtime.h>
#include <hip/hip_bf16.h>

typedef __bf16 bf16x8 __attribute__((ext_vector_type(8)));
typedef float  f32x4  __attribute__((ext_vector_type(4)));

#define UBV   35.0f
#define SUMC  150.0f

__device__ __forceinline__ float lrelu(float x) { return fmaxf(x, 0.2f * x); }

// pack 2 f32 -> 2 fp8(e4m3) in low 16 bits
__device__ __forceinline__ unsigned pk8(float a, float b) {
    return ((unsigned)__builtin_amdgcn_cvt_pk_fp8_f32(a, b, 0, false)) & 0xffffu;
}
__device__ __forceinline__ long mk64(unsigned lo, unsigned hi) {
    return (long)(((unsigned long long)hi << 32) | (unsigned long long)lo);
}
__device__ __forceinline__ void async16(void* lds_uniform, const void* gsrc) {
    __builtin_amdgcn_global_load_lds(
        (__attribute__((address_space(1))) void*)(gsrc),
        (__attribute__((address_space(3))) void*)(lds_uniform),
        16, 0, 0);
}

// ---------------------------------------------------------------------------
// sigma mapping (phase A -> phase B handoff): see R4 comments.
// (Verified numerically since R4: absmax 0.125.)
// ---------------------------------------------------------------------------

__global__ void prep_kernel(const float* __restrict__ W1, const float* __restrict__ b1,
                            const float* __restrict__ W2, const float* __restrict__ b2,
                            const float* __restrict__ W3, const float* __restrict__ b3,
                            __bf16* __restrict__ w1p, uint2* __restrict__ w2p,
                            uint2* __restrict__ w3c)
{
    int idx = blockIdx.x * blockDim.x + threadIdx.x;
    if (idx < 1664) {
        int lane = idx & 63;
        int nt = idx >> 6;
        int c16 = lane & 15, g = lane >> 4;
        int kk = nt >> 1, hh = nt & 1;
        int kap = kk * 32 + (c16 >> 2) * 8 + hh * 4 + (c16 & 3);
        bf16x8 v;
        #pragma unroll
        for (int j = 0; j < 8; ++j) {
            int k = g * 8 + j;
            float x = 0.f;
            if (kap < 400) {
                if (k < 17) x = W1[kap * 17 + k];
                else if (k == 17) x = b1[kap];
            } else if (kap == 400) {
                if (k == 17) x = 1.0f;
            }
            v[j] = (__bf16)x;
        }
        *(bf16x8*)(w1p + idx * 8) = v;
    } else if (idx < 1664 + 16640) {
        int i2 = idx - 1664;
        int fg = i2 >> 6, lane = i2 & 63;
        int q = fg / 65, rem = fg % 65;
        int t = rem / 13, kt = rem % 13;
        int c16 = lane & 15, g = lane >> 4;
        int local = t * 16 + c16;
        int ff = q * 79 + local;
        float v[8];
        #pragma unroll
        for (int j = 0; j < 8; ++j) {
            int kap = kt * 32 + g * 8 + j;
            float x = 0.f;
            if (local == 79) {
                x = (kap == 400) ? 1.0f : 0.f;
            } else if (local < 79 && ff < 300) {
                if (kap < 400) x = W2[ff * 400 + kap];
                else if (kap == 400) x = b2[ff];
            }
            v[j] = x;
        }
        uint2 d;
        d.x = pk8(v[0], v[1]) | (pk8(v[2], v[3]) << 16);
        d.y = pk8(v[4], v[5]) | (pk8(v[6], v[7]) << 16);
        w2p[i2] = d;
    } else if (idx < 1664 + 16640 + 768) {
        int i3 = idx - 1664 - 16640;
        int fg = i3 >> 6, lane = i3 & 63;
        int q = fg / 3, k2 = fg % 3;
        int o = lane & 15, g = lane >> 4;
        float v[8];
        #pragma unroll
        for (int j = 0; j < 8; ++j) {
            int t2  = 2 * k2 + (j >> 2);
            int rho = g * 4 + (j & 3);
            int local = t2 * 16 + rho;
            float x = 0.f;
            if (o < 5 && t2 < 5) {
                if (local == 79) x = b3[o] * 0.25f;
                else if (local < 79 && q * 79 + local < 300)
                    x = W3[o * 300 + q * 79 + local];
            }
            v[j] = x;
        }
        uint2 d;
        d.x = pk8(v[0], v[1]) | (pk8(v[2], v[3]) << 16);
        d.y = pk8(v[4], v[5]) | (pk8(v[6], v[7]) << 16);
        w3c[i3] = d;
    }
}

// ---------------------------------------------------------------------------
// R11 DIAGNOSTIC: R10's exact build (waves_per_eu(2,2), CONSUME macro) with
// REPS=2 idempotent repetition -> actor dispatch ~64us rises above the ~40us
// harness fills -> top-5 shows its VGPR_Count / WRITE_SIZE / MfmaUtil.
// Pre-committed reading: VGPR=128 & WRITE~45MB => attribute ignored, spill
// persists. VGPR~256 & WRITE~2.6MB => spill gone, 32us lives elsewhere.
// ---------------------------------------------------------------------------
#define REPS 2

#define CONSUME(mm)                                                            \
    {                                                                          \
        f32x4 acc0 = {0.f,0.f,0.f,0.f}, acc1 = {0.f,0.f,0.f,0.f};              \
        f32x4 acc2 = {0.f,0.f,0.f,0.f}, acc3 = {0.f,0.f,0.f,0.f};              \
        f32x4 acc4 = {0.f,0.f,0.f,0.f};                                        \
        _Pragma("unroll")                                                      \
        for (int kt = 0; kt < 13; ++kt) {                                      \
            acc0 = __builtin_amdgcn_mfma_f32_16x16x32_fp8_fp8(w2A[0][kt], frv[kt], acc0, 0, 0, 0); \
            acc1 = __builtin_amdgcn_mfma_f32_16x16x32_fp8_fp8(w2A[1][kt], frv[kt], acc1, 0, 0, 0); \
            acc2 = __builtin_amdgcn_mfma_f32_16x16x32_fp8_fp8(w2A[2][kt], frv[kt], acc2, 0, 0, 0); \
            acc3 = __builtin_amdgcn_mfma_f32_16x16x32_fp8_fp8(w2A[3][kt], frv[kt], acc3, 0, 0, 0); \
            acc4 = __builtin_amdgcn_mfma_f32_16x16x32_fp8_fp8(w2A[4][kt], frv[kt], acc4, 0, 0, 0); \
        }                                                                      \
        unsigned dw0 = pk8(lrelu(acc0[0]), lrelu(acc0[1])) | (pk8(lrelu(acc0[2]), lrelu(acc0[3])) << 16); \
        unsigned dw1 = pk8(lrelu(acc1[0]), lrelu(acc1[1])) | (pk8(lrelu(acc1[2]), lrelu(acc1[3])) << 16); \
        unsigned dw2 = pk8(lrelu(acc2[0]), lrelu(acc2[1])) | (pk8(lrelu(acc2[2]), lrelu(acc2[3])) << 16); \
        unsigned dw3 = pk8(lrelu(acc3[0]), lrelu(acc3[1])) | (pk8(lrelu(acc3[2]), lrelu(acc3[3])) << 16); \
        unsigned dw4 = pk8(lrelu(acc4[0]), lrelu(acc4[1])) | (pk8(lrelu(acc4[2]), lrelu(acc4[3])) << 16); \
        f32x4 cc = {0.f,0.f,0.f,0.f};                                          \
        cc = __builtin_amdgcn_mfma_f32_16x16x32_fp8_fp8(w3A[0], mk64(dw0, dw1), cc, 0, 0, 0); \
        cc = __builtin_amdgcn_mfma_f32_16x16x32_fp8_fp8(w3A[1], mk64(dw2, dw3), cc, 0, 0, 0); \
        cc = __builtin_amdgcn_mfma_f32_16x16x32_fp8_fp8(w3A[2], mk64(dw4, 0u),  cc, 0, 0, 0); \
        if (g == 0)      *(f32x4*)(&s_part[mm][wid][c16][0]) = cc;             \
        else if (g == 1) s_part[mm][wid][c16][4] = cc[0];                      \
    }

__global__
__attribute__((amdgpu_flat_work_group_size(256, 256), amdgpu_waves_per_eu(2, 2)))
void actor_kernel(const float* __restrict__ state,
                  const __bf16* __restrict__ w1p,
                  const uint2* __restrict__ w2p,
                  const uint2* __restrict__ w3c,
                  float* __restrict__ out)
{
    __shared__ __align__(16) __bf16 s_w1[1664 * 8];   // 26,624B W1p mirror
    __shared__ uint2 s_h1[4][13][64];                 // 26,624B fp8 h1 B-frags
    __shared__ float s_part[4][4][16][8];             //  8,192B [m][q][row][o]

    const int tid = threadIdx.x;
    const int wid = tid >> 6;            // wave = quarter = own m-tile
    const int ln  = tid & 63;
    const int g   = ln >> 4, c16 = ln & 15;
    const int brow = blockIdx.x << 6;    // 64 rows/block

    // ---- stage W1p -> LDS once (26 chunks of 1KB; wave-uniform dest) ----
    {
        char* lb = (char*)s_w1;
        const char* gb = (const char*)w1p;
        #pragma unroll
        for (int i = wid; i < 26; i += 4)
            async16(lb + i * 1024, gb + i * 1024 + ln * 16);
    }
    __syncthreads();   // W1 staged

    #pragma unroll 1
    for (int rep = 0; rep < REPS; ++rep) {
        // opaque zero: prevents LICM from hoisting per-rep reloads
        int zz = rep;
        asm volatile("" : "+v"(zz));
        const int z0 = zz >> 20;         // always 0 at runtime

        // ---- resident W2 quarter + W3 coeffs ----
        long w2A[5][13];
        long w3A[3];
        {
            const long* gw2 = (const long*)w2p + z0;
            #pragma unroll
            for (int t = 0; t < 5; ++t)
                #pragma unroll
                for (int kt = 0; kt < 13; ++kt)
                    w2A[t][kt] = gw2[((wid * 5 + t) * 13 + kt) * 64 + ln];
            const long* gw3 = (const long*)w3c + z0;
            #pragma unroll
            for (int k2 = 0; k2 < 3; ++k2)
                w3A[k2] = gw3[(wid * 3 + k2) * 64 + ln];
        }

        // ---- state A-frag ----
        bf16x8 sb;
        {
            const float* sp = state + (brow + wid * 16 + c16) * 17 + z0;
            if (g == 0) {
                #pragma unroll
                for (int j = 0; j < 8; ++j) sb[j] = (__bf16)sp[j];
            } else if (g == 1) {
                #pragma unroll
                for (int j = 0; j < 8; ++j) sb[j] = (__bf16)sp[8 + j];
            } else if (g == 2) {
                sb[0] = (__bf16)sp[16];
                sb[1] = (__bf16)1.0f;          // bias carrier k=17
                #pragma unroll
                for (int j = 2; j < 8; ++j) sb[j] = (__bf16)0.f;
            } else {
                #pragma unroll
                for (int j = 0; j < 8; ++j) sb[j] = (__bf16)0.f;
            }
        }

        // ---- Phase A: produce h1 for m-tile = wid (frags stay in frv) ----
        long frv[13];
        #pragma unroll
        for (int kt = 0; kt < 13; ++kt) {
            bf16x8 we = *(const bf16x8*)(s_w1 + ((2 * kt) * 64 + ln) * 8);
            bf16x8 wo = *(const bf16x8*)(s_w1 + ((2 * kt + 1) * 64 + ln) * 8);
            f32x4 ae = {0.f, 0.f, 0.f, 0.f}, ao = {0.f, 0.f, 0.f, 0.f};
            ae = __builtin_amdgcn_mfma_f32_16x16x32_bf16(we, sb, ae, 0, 0, 0);
            ao = __builtin_amdgcn_mfma_f32_16x16x32_bf16(wo, sb, ao, 0, 0, 0);
            uint2 d;
            d.x = pk8(lrelu(ae[0]), lrelu(ae[1])) | (pk8(lrelu(ae[2]), lrelu(ae[3])) << 16);
            d.y = pk8(lrelu(ao[0]), lrelu(ao[1])) | (pk8(lrelu(ao[2]), lrelu(ao[3])) << 16);
            s_h1[wid][kt][ln] = d;
            frv[kt] = mk64(d.x, d.y);
        }

        // ---- Phase B/C for own tile: pure-register path, pre-barrier ----
        CONSUME(wid)

        __syncthreads();   // all 4 h1 tiles visible

        // ---- sibling tiles: rotation covers each (m, quarter) once ----
        #pragma unroll 1
        for (int s = 1; s < 4; ++s) {
            const int m = (wid + s) & 3;
            #pragma unroll
            for (int kt = 0; kt < 13; ++kt)
                frv[kt] = *(const long*)(&s_h1[m][kt][ln]);
            CONSUME(m)
        }

        __syncthreads();   // all partials visible; s_h1 free for next rep

        // ---- Epilogue: wave wid -> its m-tile's 16 rows; exact QP ----
        if (ln < 16) {
            f32x4 sv = {0.f, 0.f, 0.f, 0.f};
            float s4 = 0.f;
            #pragma unroll
            for (int qq = 0; qq < 4; ++qq) {
                sv += *(const f32x4*)(&s_part[wid][qq][ln][0]);
                s4 += s_part[wid][qq][ln][4];
            }
            float v[5];
            v[0] = -lrelu(sv[0]); v[1] = -lrelu(sv[1]);
            v[2] = -lrelu(sv[2]); v[3] = -lrelu(sv[3]);
            v[4] = -lrelu(s4);

            float bp[10];
            #pragma unroll
            for (int i = 0; i < 5; ++i) { bp[i] = v[i]; bp[i + 5] = v[i] - UBV; }
            float blo = -1e30f, glo = 0.f;
            #pragma unroll
            for (int j = 0; j < 10; ++j) {
                float b = bp[j];
                float gsum = 0.f;
                #pragma unroll
                for (int i = 0; i < 5; ++i) {
                    float zc = v[i] - b;
                    zc = fminf(fmaxf(zc, 0.f), UBV);
                    gsum += zc;
                }
                if (gsum >= SUMC && b > blo) { blo = b; glo = gsum; }
            }
            float bhi = 1e30f;
            #pragma unroll
            for (int j = 0; j < 10; ++j) {
                float b = bp[j];
                if (b > blo && b < bhi) bhi = b;
            }
            float mid = 0.5f * (blo + bhi);
            int nfree = 0;
            #pragma unroll
            for (int i = 0; i < 5; ++i)
                nfree += (v[i] > mid && v[i] < mid + UBV) ? 1 : 0;
            float nu = (nfree > 0) ? blo + (glo - SUMC) / (float)nfree : blo;

            int row = brow + wid * 16 + ln;
            #pragma unroll
            for (int o = 0; o < 5; ++o) {
                float zf = v[o] - nu;
                zf = fminf(fmaxf(zf, 0.f), UBV);
                out[row * 5 + o] = zf;
            }
        }
        // rep-crossing race audit (empirically clean in R9, absmax 0.125):
        // next rep's s_h1[wid]/s_part[*][wid] writes touch only m=wid slots,
        // which this rep's other-wave readers finished before the barriers.
    }
}

extern "C" void kernel_launch(void* const* d_in, const int* in_sizes, int n_in,
                              void* d_out, int out_size, void* d_ws, size_t ws_size,
                              hipStream_t stream) {
    const float* state = (const float*)d_in[0];
    const float* W1    = (const float*)d_in[1];
    const float* b1    = (const float*)d_in[2];
    const float* W2    = (const float*)d_in[3];
    const float* b2    = (const float*)d_in[4];
    const float* W3    = (const float*)d_in[5];
    const float* b3    = (const float*)d_in[6];
    float* out = (float*)d_out;

    char* base = (char*)d_ws;
    __bf16* w1p = (__bf16*)base;                   // 26,624B
    uint2*  w2p = (uint2*)(base + 26624);          // 133,120B
    uint2*  w3c = (uint2*)(base + 26624 + 133120); // 6,144B

    const int total = 1664 + 16640 + 768;
    prep_kernel<<<(total + 255) / 256, 256, 0, stream>>>(W1, b1, W2, b2, W3, b3,
                                                         w1p, w2p, w3c);

    int B = in_sizes[0] / 17;                      // 65536
    actor_kernel<<<B / 64, 256, 0, stream>>>(state, w1p, w2p, w3c, out);
}

// Round 12
// 29.721 us; speedup vs baseline: 2.6148x; 2.6148x over previous
//
#include <hip/hip_runtime.h>
#include <hip/hip_bf16.h>

typedef __bf16 bf16x8 __attribute__((ext_vector_type(8)));
typedef float  f32x4  __attribute__((ext_vector_type(4)));

#define UBV   35.0f
#define SUMC  150.0f

__device__ __forceinline__ float lrelu(float x) { return fmaxf(x, 0.2f * x); }

// pack 2 f32 -> 2 fp8(e4m3) in low 16 bits
__device__ __forceinline__ unsigned pk8(float a, float b) {
    return ((unsigned)__builtin_amdgcn_cvt_pk_fp8_f32(a, b, 0, false)) & 0xffffu;
}
__device__ __forceinline__ long mk64(unsigned lo, unsigned hi) {
    return (long)(((unsigned long long)hi << 32) | (unsigned long long)lo);
}
__device__ __forceinline__ void async16(void* lds_uniform, const void* gsrc) {
    __builtin_amdgcn_global_load_lds(
        (__attribute__((address_space(1))) void*)(gsrc),
        (__attribute__((address_space(3))) void*)(lds_uniform),
        16, 0, 0);
}

// ---------------------------------------------------------------------------
// sigma mapping (phase A -> phase B handoff): see R4 comments.
// (Verified numerically since R4: absmax 0.125. Prep is byte-identical.)
// ---------------------------------------------------------------------------

__global__ void prep_kernel(const float* __restrict__ W1, const float* __restrict__ b1,
                            const float* __restrict__ W2, const float* __restrict__ b2,
                            const float* __restrict__ W3, const float* __restrict__ b3,
                            __bf16* __restrict__ w1p, uint2* __restrict__ w2p,
                            uint2* __restrict__ w3c)
{
    int idx = blockIdx.x * blockDim.x + threadIdx.x;
    if (idx < 1664) {
        int lane = idx & 63;
        int nt = idx >> 6;
        int c16 = lane & 15, g = lane >> 4;
        int kk = nt >> 1, hh = nt & 1;
        int kap = kk * 32 + (c16 >> 2) * 8 + hh * 4 + (c16 & 3);
        bf16x8 v;
        #pragma unroll
        for (int j = 0; j < 8; ++j) {
            int k = g * 8 + j;
            float x = 0.f;
            if (kap < 400) {
                if (k < 17) x = W1[kap * 17 + k];
                else if (k == 17) x = b1[kap];
            } else if (kap == 400) {
                if (k == 17) x = 1.0f;
            }
            v[j] = (__bf16)x;
        }
        *(bf16x8*)(w1p + idx * 8) = v;
    } else if (idx < 1664 + 16640) {
        int i2 = idx - 1664;
        int fg = i2 >> 6, lane = i2 & 63;
        int q = fg / 65, rem = fg % 65;
        int t = rem / 13, kt = rem % 13;
        int c16 = lane & 15, g = lane >> 4;
        int local = t * 16 + c16;
        int ff = q * 79 + local;
        float v[8];
        #pragma unroll
        for (int j = 0; j < 8; ++j) {
            int kap = kt * 32 + g * 8 + j;
            float x = 0.f;
            if (local == 79) {
                x = (kap == 400) ? 1.0f : 0.f;
            } else if (local < 79 && ff < 300) {
                if (kap < 400) x = W2[ff * 400 + kap];
                else if (kap == 400) x = b2[ff];
            }
            v[j] = x;
        }
        uint2 d;
        d.x = pk8(v[0], v[1]) | (pk8(v[2], v[3]) << 16);
        d.y = pk8(v[4], v[5]) | (pk8(v[6], v[7]) << 16);
        w2p[i2] = d;
    } else if (idx < 1664 + 16640 + 768) {
        int i3 = idx - 1664 - 16640;
        int fg = i3 >> 6, lane = i3 & 63;
        int q = fg / 3, k2 = fg % 3;
        int o = lane & 15, g = lane >> 4;
        float v[8];
        #pragma unroll
        for (int j = 0; j < 8; ++j) {
            int t2  = 2 * k2 + (j >> 2);
            int rho = g * 4 + (j & 3);
            int local = t2 * 16 + rho;
            float x = 0.f;
            if (o < 5 && t2 < 5) {
                if (local == 79) x = b3[o] * 0.25f;
                else if (local < 79 && q * 79 + local < 300)
                    x = W3[o * 300 + q * 79 + local];
            }
            v[j] = x;
        }
        uint2 d;
        d.x = pk8(v[0], v[1]) | (pk8(v[2], v[3]) << 16);
        d.y = pk8(v[4], v[5]) | (pk8(v[6], v[7]) << 16);
        w3c[i3] = d;
    }
}

// ---------------------------------------------------------------------------
// Actor R12: 1024 blocks x 256 threads (4 waves), 64 rows/block.
// R11 verdict: 130-VGPR resident W2 is unallocatable (VGPR_Count pinned at
// 128, ~64MB scratch spill/dispatch). Inverted residency: h1 frags (frv[13],
// 26 regs) stay in registers; W2 streams quarter-by-quarter through ONE
// 33,280B LDS buffer shared by all 4 waves (union with W1p during phase A).
// s_h1 / s_part / shfl-reduce eliminated; quarter sums accumulate in regs.
// Peak liveness ~100 < 128 -> __launch_bounds__(256,4): 4 blocks/CU,
// 16 waves/CU (4/EU). Numerics byte-identical to R4-R11 (absmax 0.125).
// ---------------------------------------------------------------------------
__global__ __launch_bounds__(256, 4)
void actor_kernel(const float* __restrict__ state,
                  const __bf16* __restrict__ w1p,
                  const uint2* __restrict__ w2p,
                  const uint2* __restrict__ w3c,
                  float* __restrict__ out)
{
    __shared__ __align__(16) char s_mem[33280];   // W1p (26,624B) then W2 quarter

    const int tid = threadIdx.x;
    const int wid = tid >> 6;            // wave = own m-tile
    const int ln  = tid & 63;
    const int g   = ln >> 4, c16 = ln & 15;
    const int brow = blockIdx.x << 6;    // 64 rows/block

    // ---- stage W1p -> LDS (26 chunks of 1KB; wave-uniform dest base) ----
    {
        char* lb = s_mem;
        const char* gb = (const char*)w1p;
        #pragma unroll
        for (int i = wid; i < 26; i += 4)
            async16(lb + i * 1024, gb + i * 1024 + ln * 16);
    }

    // ---- state A-frag (4 regs, built pre-barrier; hides load latency) ----
    bf16x8 sb;
    {
        const float* sp = state + (brow + wid * 16 + c16) * 17;
        if (g == 0) {
            #pragma unroll
            for (int j = 0; j < 8; ++j) sb[j] = (__bf16)sp[j];
        } else if (g == 1) {
            #pragma unroll
            for (int j = 0; j < 8; ++j) sb[j] = (__bf16)sp[8 + j];
        } else if (g == 2) {
            sb[0] = (__bf16)sp[16];
            sb[1] = (__bf16)1.0f;          // bias carrier k=17
            #pragma unroll
            for (int j = 2; j < 8; ++j) sb[j] = (__bf16)0.f;
        } else {
            #pragma unroll
            for (int j = 0; j < 8; ++j) sb[j] = (__bf16)0.f;
        }
    }

    __syncthreads();   // W1 staged

    // ---- Phase A: h1 for m-tile = wid; frv[13] stays in registers ----
    long frv[13];
    #pragma unroll
    for (int kt = 0; kt < 13; ++kt) {
        bf16x8 we = *(const bf16x8*)(s_mem + ((2 * kt) * 64 + ln) * 16);
        bf16x8 wo = *(const bf16x8*)(s_mem + ((2 * kt + 1) * 64 + ln) * 16);
        f32x4 ae = {0.f, 0.f, 0.f, 0.f}, ao = {0.f, 0.f, 0.f, 0.f};
        ae = __builtin_amdgcn_mfma_f32_16x16x32_bf16(we, sb, ae, 0, 0, 0);
        ao = __builtin_amdgcn_mfma_f32_16x16x32_bf16(wo, sb, ao, 0, 0, 0);
        frv[kt] = mk64(
            pk8(lrelu(ae[0]), lrelu(ae[1])) | (pk8(lrelu(ae[2]), lrelu(ae[3])) << 16),
            pk8(lrelu(ao[0]), lrelu(ao[1])) | (pk8(lrelu(ao[2]), lrelu(ao[3])) << 16));
    }

    __syncthreads();   // all waves done reading s_w1; region free for W2

    // ---- q-loop: stage quarter q into LDS, consume with register h1 ----
    f32x4 ccs = {0.f, 0.f, 0.f, 0.f};
    const long* gw3 = (const long*)w3c;

    #pragma unroll 1
    for (int q = 0; q < 4; ++q) {
        // stage 33,280B quarter: 32 x 1KB async + 512B tail
        {
            char* lb = s_mem;
            const char* gb = (const char*)w2p + q * 33280;
            #pragma unroll
            for (int i = wid; i < 32; i += 4)
                async16(lb + i * 1024, gb + i * 1024 + ln * 16);
            if (tid < 64)
                *(uint2*)(s_mem + 32768 + tid * 8) =
                    *(const uint2*)(gb + 32768 + tid * 8);
        }
        // w3 frags for this quarter (3 x 8B, L2-hot)
        long w3q0 = gw3[(q * 3 + 0) * 64 + ln];
        long w3q1 = gw3[(q * 3 + 1) * 64 + ln];
        long w3q2 = gw3[(q * 3 + 2) * 64 + ln];

        __syncthreads();   // quarter staged

        const long* wq = (const long*)s_mem;
        f32x4 acc0 = {0.f,0.f,0.f,0.f}, acc1 = {0.f,0.f,0.f,0.f};
        f32x4 acc2 = {0.f,0.f,0.f,0.f}, acc3 = {0.f,0.f,0.f,0.f};
        f32x4 acc4 = {0.f,0.f,0.f,0.f};
        #pragma unroll
        for (int kt = 0; kt < 13; ++kt) {
            long f0 = wq[(0 * 13 + kt) * 64 + ln];
            long f1 = wq[(1 * 13 + kt) * 64 + ln];
            long f2 = wq[(2 * 13 + kt) * 64 + ln];
            long f3 = wq[(3 * 13 + kt) * 64 + ln];
            long f4 = wq[(4 * 13 + kt) * 64 + ln];
            acc0 = __builtin_amdgcn_mfma_f32_16x16x32_fp8_fp8(f0, frv[kt], acc0, 0, 0, 0);
            acc1 = __builtin_amdgcn_mfma_f32_16x16x32_fp8_fp8(f1, frv[kt], acc1, 0, 0, 0);
            acc2 = __builtin_amdgcn_mfma_f32_16x16x32_fp8_fp8(f2, frv[kt], acc2, 0, 0, 0);
            acc3 = __builtin_amdgcn_mfma_f32_16x16x32_fp8_fp8(f3, frv[kt], acc3, 0, 0, 0);
            acc4 = __builtin_amdgcn_mfma_f32_16x16x32_fp8_fp8(f4, frv[kt], acc4, 0, 0, 0);
        }
        unsigned dw0 = pk8(lrelu(acc0[0]), lrelu(acc0[1])) | (pk8(lrelu(acc0[2]), lrelu(acc0[3])) << 16);
        unsigned dw1 = pk8(lrelu(acc1[0]), lrelu(acc1[1])) | (pk8(lrelu(acc1[2]), lrelu(acc1[3])) << 16);
        unsigned dw2 = pk8(lrelu(acc2[0]), lrelu(acc2[1])) | (pk8(lrelu(acc2[2]), lrelu(acc2[3])) << 16);
        unsigned dw3 = pk8(lrelu(acc3[0]), lrelu(acc3[1])) | (pk8(lrelu(acc3[2]), lrelu(acc3[3])) << 16);
        unsigned dw4 = pk8(lrelu(acc4[0]), lrelu(acc4[1])) | (pk8(lrelu(acc4[2]), lrelu(acc4[3])) << 16);
        f32x4 cc = {0.f, 0.f, 0.f, 0.f};
        cc = __builtin_amdgcn_mfma_f32_16x16x32_fp8_fp8(w3q0, mk64(dw0, dw1), cc, 0, 0, 0);
        cc = __builtin_amdgcn_mfma_f32_16x16x32_fp8_fp8(w3q1, mk64(dw2, dw3), cc, 0, 0, 0);
        cc = __builtin_amdgcn_mfma_f32_16x16x32_fp8_fp8(w3q2, mk64(dw4, 0u),  cc, 0, 0, 0);
        ccs += cc;

        __syncthreads();   // consumed; safe to restage next quarter
    }

    // ---- Epilogue: bring o=4 to g=0 lanes, exact QP, store ----
    float v4all = __shfl_xor(ccs[0], 16);   // lane r (g=0) <- lane r+16's ccs[0]

    if (ln < 16) {
        float v[5];
        v[0] = -lrelu(ccs[0]); v[1] = -lrelu(ccs[1]);
        v[2] = -lrelu(ccs[2]); v[3] = -lrelu(ccs[3]);
        v[4] = -lrelu(v4all);

        float bp[10];
        #pragma unroll
        for (int i = 0; i < 5; ++i) { bp[i] = v[i]; bp[i + 5] = v[i] - UBV; }
        float blo = -1e30f, glo = 0.f;
        #pragma unroll
        for (int j = 0; j < 10; ++j) {
            float b = bp[j];
            float gsum = 0.f;
            #pragma unroll
            for (int i = 0; i < 5; ++i) {
                float zc = v[i] - b;
                zc = fminf(fmaxf(zc, 0.f), UBV);
                gsum += zc;
            }
            if (gsum >= SUMC && b > blo) { blo = b; glo = gsum; }
        }
        float bhi = 1e30f;
        #pragma unroll
        for (int j = 0; j < 10; ++j) {
            float b = bp[j];
            if (b > blo && b < bhi) bhi = b;
        }
        float mid = 0.5f * (blo + bhi);
        int nfree = 0;
        #pragma unroll
        for (int i = 0; i < 5; ++i)
            nfree += (v[i] > mid && v[i] < mid + UBV) ? 1 : 0;
        float nu = (nfree > 0) ? blo + (glo - SUMC) / (float)nfree : blo;

        int row = brow + wid * 16 + ln;
        #pragma unroll
        for (int o = 0; o < 5; ++o) {
            float zf = v[o] - nu;
            zf = fminf(fmaxf(zf, 0.f), UBV);
            out[row * 5 + o] = zf;
        }
    }
}

extern "C" void kernel_launch(void* const* d_in, const int* in_sizes, int n_in,
                              void* d_out, int out_size, void* d_ws, size_t ws_size,
                              hipStream_t stream) {
    const float* state = (const float*)d_in[0];
    const float* W1    = (const float*)d_in[1];
    const float* b1    = (const float*)d_in[2];
    const float* W2    = (const float*)d_in[3];
    const float* b2    = (const float*)d_in[4];
    const float* W3    = (const float*)d_in[5];
    const float* b3    = (const float*)d_in[6];
    float* out = (float*)d_out;

    char* base = (char*)d_ws;
    __bf16* w1p = (__bf16*)base;                   // 26,624B
    uint2*  w2p = (uint2*)(base + 26624);          // 133,120B
    uint2*  w3c = (uint2*)(base + 26624 + 133120); // 6,144B

    const int total = 1664 + 16640 + 768;
    prep_kernel<<<(total + 255) / 256, 256, 0, stream>>>(W1, b1, W2, b2, W3, b3,
                                                         w1p, w2p, w3c);

    int B = in_sizes[0] / 17;                      // 65536
    actor_kernel<<<B / 64, 256, 0, stream>>>(state, w1p, w2p, w3c, out);
}